// Round 9
// baseline (161.393 us; speedup 1.0000x reference)
//
#include <hip/hip_runtime.h>
#include <hip/hip_fp16.h>
#include <cstring>

namespace {

constexpr int    TT     = 2048;
constexpr int    BB     = 128;
constexpr int    CHUNK  = 8;                  // timesteps per chunk (shfl scan width)
constexpr int    NCHUNK = TT / CHUNK;         // 256 chunks per batch
constexpr float  DT     = 0.02f;
constexpr size_t HALF   = (size_t)TT * BB * 16;   // floats per (real|imag) half of d_out

// native vector type accepted by __builtin_nontemporal_*
typedef float vf4 __attribute__((ext_vector_type(4)));

// C = A @ B, complex 4x4, row-major flat [16]
__device__ __forceinline__ void cmm(const float* __restrict__ ar, const float* __restrict__ ai,
                                    const float* __restrict__ br, const float* __restrict__ bi,
                                    float* __restrict__ cr, float* __restrict__ ci) {
#pragma unroll
    for (int i = 0; i < 4; ++i) {
#pragma unroll
        for (int j = 0; j < 4; ++j) {
            float sr = 0.f, si = 0.f;
#pragma unroll
            for (int k = 0; k < 4; ++k) {
                const float xr = ar[i * 4 + k], xi = ai[i * 4 + k];
                const float yr = br[k * 4 + j], yi = bi[k * 4 + j];
                sr = fmaf(xr, yr, sr);
                sr = fmaf(-xi, yi, sr);
                si = fmaf(xr, yi, si);
                si = fmaf(xi, yr, si);
            }
            cr[i * 4 + j] = sr;
            ci[i * 4 + j] = si;
        }
    }
}

// fp16 RNE pack: two f32 -> one uint (lo = a, hi = b)
__device__ __forceinline__ unsigned int pkh(float a, float b) {
    __half2 h = __floats2half2_rn(a, b);
    unsigned int u;
    __builtin_memcpy(&u, &h, 4);
    return u;
}
__device__ __forceinline__ float2 uph(unsigned int u) {
    __half2 h;
    __builtin_memcpy(&h, &u, 4);
    return __half22float2(h);
}

} // namespace

// ---------------------------------------------------------------------------
// kA: expm (deg-4 PS Taylor) + 8-lane Kogge-Stone chunk prefix.
//   Scan shuffle: src = lane-d (clamped), pred = sub>=d  [R6-verified form;
//   the xor variant is WRONG: sub-d != sub^d unless bit d is set in sub].
//   gid = b*TT + t -> H read (nontemporal) and L write fully coalesced.
//   L fp16-RNE packed: 4 uint4 per matrix (re 2, im 2) at [b][t].
// ---------------------------------------------------------------------------
__global__ __launch_bounds__(256) void kA_expm_scan(const float* __restrict__ hr,
                                                    const float* __restrict__ hi,
                                                    uint4* __restrict__ L,
                                                    float* __restrict__ totals) {
    const int gid  = blockIdx.x * 256 + threadIdx.x;  // b*TT + t
    const int b    = gid >> 11;
    const int t    = gid & (TT - 1);
    const int sub  = t & (CHUNK - 1);
    const int c    = t >> 3;                          // chunk within batch
    const int lane = threadIdx.x & 63;

    // ---- load A = -i*DT*H: a_r = DT*hi, a_i = -DT*hr (coalesced, nontemporal)
    float a_r[16], a_i[16];
    {
        const vf4* p4r = reinterpret_cast<const vf4*>(hr) + (size_t)gid * 4;
        const vf4* p4i = reinterpret_cast<const vf4*>(hi) + (size_t)gid * 4;
#pragma unroll
        for (int v = 0; v < 4; ++v) {
            const vf4 rr = __builtin_nontemporal_load(p4r + v);
            const vf4 im = __builtin_nontemporal_load(p4i + v);
#pragma unroll
            for (int e = 0; e < 4; ++e) {
                a_r[v * 4 + e] = DT * im[e];
                a_i[v * 4 + e] = -DT * rr[e];
            }
        }
    }

    // ---- expm deg-4 PS: E = I + A + A2 @ (I/2 + A/6 + A2/24)
    float er[16], ei[16];
    {
        float a2r[16], a2i[16];
        cmm(a_r, a_i, a_r, a_i, a2r, a2i);
        float tr[16], ti[16];
#pragma unroll
        for (int e = 0; e < 16; ++e) {
            const float d = (e % 5 == 0) ? 1.0f : 0.0f;
            tr[e] = fmaf(a_r[e], 1.f / 6.f, d * 0.5f);
            tr[e] = fmaf(a2r[e], 1.f / 24.f, tr[e]);
            ti[e] = a_i[e] * (1.f / 6.f);
            ti[e] = fmaf(a2i[e], 1.f / 24.f, ti[e]);
        }
        cmm(a2r, a2i, tr, ti, er, ei);
#pragma unroll
        for (int e = 0; e < 16; ++e) {
            const float d = (e % 5 == 0) ? 1.0f : 0.0f;
            er[e] = er[e] + d + a_r[e];
            ei[e] = ei[e] + a_i[e];
        }
    }

    // ---- 8-lane Kogge-Stone inclusive prefix (3 rounds), verified form
#pragma unroll
    for (int d = 1; d < CHUNK; d <<= 1) {
        int src = lane - d;
        if (src < 0) src = 0;               // clamped junk, discarded by select
        float qr[16], qi[16];
#pragma unroll
        for (int e = 0; e < 16; ++e) {
            qr[e] = __shfl(er[e], src, 64);
            qi[e] = __shfl(ei[e], src, 64);
        }
        float nr[16], ni[16];
        cmm(er, ei, qr, qi, nr, ni);
        const bool pred = (sub >= d);
#pragma unroll
        for (int e = 0; e < 16; ++e) {
            er[e] = pred ? nr[e] : er[e];
            ei[e] = pred ? ni[e] : ei[e];
        }
    }

    // ---- chunk totals (f32)
    if (sub == CHUNK - 1) {
        float* tp = totals + ((size_t)b * NCHUNK + c) * 32;
#pragma unroll
        for (int e = 0; e < 16; ++e) {
            tp[e]      = er[e];
            tp[16 + e] = ei[e];
        }
    }

    // ---- L fp16-RNE packed, coalesced: 4 uint4 per matrix (regular store:
    // we WANT L resident in this XCD's L2 for kD)
    {
        uint4 w0, w1, w2, w3;
        w0.x = pkh(er[0],  er[1]);   w0.y = pkh(er[2],  er[3]);
        w0.z = pkh(er[4],  er[5]);   w0.w = pkh(er[6],  er[7]);
        w1.x = pkh(er[8],  er[9]);   w1.y = pkh(er[10], er[11]);
        w1.z = pkh(er[12], er[13]);  w1.w = pkh(er[14], er[15]);
        w2.x = pkh(ei[0],  ei[1]);   w2.y = pkh(ei[2],  ei[3]);
        w2.z = pkh(ei[4],  ei[5]);   w2.w = pkh(ei[6],  ei[7]);
        w3.x = pkh(ei[8],  ei[9]);   w3.y = pkh(ei[10], ei[11]);
        w3.z = pkh(ei[12], ei[13]);  w3.w = pkh(ei[14], ei[15]);
        uint4* Lp = L + (size_t)gid * 4;
        Lp[0] = w0; Lp[1] = w1; Lp[2] = w2; Lp[3] = w3;
    }
}

// ---------------------------------------------------------------------------
// kC: carries. One block per batch (256 threads = 256 chunks).
//   M[0] = state0[b], M[ct] = total[b][ct-1]; 8-round KS in LDS (SoA).
// ---------------------------------------------------------------------------
__global__ __launch_bounds__(256) void kC_carry(const float* __restrict__ totals,
                                                const float* __restrict__ sr,
                                                const float* __restrict__ si,
                                                float* __restrict__ carry) {
    __shared__ float sRe[16][NCHUNK];
    __shared__ float sIm[16][NCHUNK];

    const int ct = threadIdx.x;             // 0..255
    const int b  = blockIdx.x;

    float pr[16], pi[16];
    if (ct == 0) {
#pragma unroll
        for (int e = 0; e < 16; ++e) {
            pr[e] = sr[b * 16 + e];
            pi[e] = si[b * 16 + e];
        }
    } else {
        const float* tp = totals + ((size_t)b * NCHUNK + ct - 1) * 32;
#pragma unroll
        for (int e = 0; e < 16; ++e) {
            pr[e] = tp[e];
            pi[e] = tp[16 + e];
        }
    }

#pragma unroll
    for (int e = 0; e < 16; ++e) {
        sRe[e][ct] = pr[e];
        sIm[e][ct] = pi[e];
    }
    __syncthreads();

#pragma unroll
    for (int d = 1; d < NCHUNK; d <<= 1) {
        if (ct >= d) {
            float qr[16], qi[16];
#pragma unroll
            for (int e = 0; e < 16; ++e) {
                qr[e] = sRe[e][ct - d];
                qi[e] = sIm[e][ct - d];
            }
            float nr[16], ni[16];
            cmm(pr, pi, qr, qi, nr, ni);
#pragma unroll
            for (int e = 0; e < 16; ++e) {
                pr[e] = nr[e];
                pi[e] = ni[e];
            }
        }
        __syncthreads();
        if (ct >= d) {
#pragma unroll
            for (int e = 0; e < 16; ++e) {
                sRe[e][ct] = pr[e];
                sIm[e][ct] = pi[e];
            }
        }
        __syncthreads();
    }

    float* cp = carry + ((size_t)b * NCHUNK + ct) * 32;
#pragma unroll
    for (int e = 0; e < 16; ++e) {
        cp[e]      = pr[e];
        cp[16 + e] = pi[e];
    }
}

// ---------------------------------------------------------------------------
// kD: out[t,b] = L[b,t] @ carry[b][t/8], [b][t] -> [t][b] via LDS transpose.
// XCD-aligned block swizzle: tile (tileT,tileB)'s L lines were written by kA
// blocks j = b*8 + tileT/16, all on XCD (tileT/16)%8. Map g%8 == that XCD so
// the L read hits the writer XCD's L2. Tile: 16t x 16b matrices / block.
// ---------------------------------------------------------------------------
__global__ __launch_bounds__(256) void kD_final(const uint4* __restrict__ L,
                                                const float* __restrict__ carry,
                                                float* __restrict__ out) {
    __shared__ float lds[32 * 16 * 17];     // [e 0..31][bloc][tloc(+pad)]

    const int g     = blockIdx.x;           // 0..1023
    const int tileT = (g & 7) * 16 + ((g >> 3) & 15);   // XCD-aligned: (tileT/16)%8 == g%8
    const int tileB = g >> 7;               // 0..7
    const int t0 = tileT * 16, b0 = tileB * 16;
    const int tid = threadIdx.x;

    // ---- phase 1: read L (fp16) coalesced, multiply by carry, stage to LDS
    {
        const int bloc = tid >> 4, tloc = tid & 15;
        const int tt = t0 + tloc;
        const size_t gi = ((size_t)(b0 + bloc) * TT + tt);

        const uint4* Lp = L + gi * 4;
        const uint4 w0 = Lp[0], w1 = Lp[1], w2 = Lp[2], w3 = Lp[3];
        float l_r[16], l_i[16];
        {
            float2 p;
            p = uph(w0.x); l_r[0]  = p.x; l_r[1]  = p.y;
            p = uph(w0.y); l_r[2]  = p.x; l_r[3]  = p.y;
            p = uph(w0.z); l_r[4]  = p.x; l_r[5]  = p.y;
            p = uph(w0.w); l_r[6]  = p.x; l_r[7]  = p.y;
            p = uph(w1.x); l_r[8]  = p.x; l_r[9]  = p.y;
            p = uph(w1.y); l_r[10] = p.x; l_r[11] = p.y;
            p = uph(w1.z); l_r[12] = p.x; l_r[13] = p.y;
            p = uph(w1.w); l_r[14] = p.x; l_r[15] = p.y;
            p = uph(w2.x); l_i[0]  = p.x; l_i[1]  = p.y;
            p = uph(w2.y); l_i[2]  = p.x; l_i[3]  = p.y;
            p = uph(w2.z); l_i[4]  = p.x; l_i[5]  = p.y;
            p = uph(w2.w); l_i[6]  = p.x; l_i[7]  = p.y;
            p = uph(w3.x); l_i[8]  = p.x; l_i[9]  = p.y;
            p = uph(w3.y); l_i[10] = p.x; l_i[11] = p.y;
            p = uph(w3.z); l_i[12] = p.x; l_i[13] = p.y;
            p = uph(w3.w); l_i[14] = p.x; l_i[15] = p.y;
        }

        float c_r[16], c_i[16];
        const float* cp = carry + ((size_t)(b0 + bloc) * NCHUNK + (tt >> 3)) * 32;
#pragma unroll
        for (int e = 0; e < 16; ++e) {
            c_r[e] = cp[e];
            c_i[e] = cp[16 + e];
        }

        float o_r[16], o_i[16];
        cmm(l_r, l_i, c_r, c_i, o_r, o_i);

        const int slot = bloc * 17 + tloc;
#pragma unroll
        for (int e = 0; e < 16; ++e) {
            lds[e * 272 + slot]        = o_r[e];
            lds[(e + 16) * 272 + slot] = o_i[e];
        }
    }
    __syncthreads();

    // ---- phase 2: read transposed from LDS, write out coalesced (nontemporal)
    {
        const int u = tid >> 4;             // t offset in tile
        const int v = tid & 15;             // b offset in tile
        const int slot = v * 17 + u;

        float r2[16], i2[16];
#pragma unroll
        for (int e = 0; e < 16; ++e) {
            r2[e] = lds[e * 272 + slot];
            i2[e] = lds[(e + 16) * 272 + slot];
        }

        const size_t oi = ((size_t)(t0 + u) * BB + (b0 + v)) * 16;
        vf4* orp = reinterpret_cast<vf4*>(out + oi);
        vf4* oip = reinterpret_cast<vf4*>(out + HALF + oi);
#pragma unroll
        for (int w = 0; w < 4; ++w) {
            vf4 vr = {r2[w * 4 + 0], r2[w * 4 + 1], r2[w * 4 + 2], r2[w * 4 + 3]};
            vf4 vi = {i2[w * 4 + 0], i2[w * 4 + 1], i2[w * 4 + 2], i2[w * 4 + 3]};
            __builtin_nontemporal_store(vr, orp + w);
            __builtin_nontemporal_store(vi, oip + w);
        }
    }
}

extern "C" void kernel_launch(void* const* d_in, const int* in_sizes, int n_in,
                              void* d_out, int out_size, void* d_ws, size_t ws_size,
                              hipStream_t stream) {
    const float* hr = (const float*)d_in[0];
    const float* hi = (const float*)d_in[1];
    const float* sr = (const float*)d_in[2];
    const float* si = (const float*)d_in[3];
    float* out    = (float*)d_out;
    float* totals = (float*)d_ws;                                   // 4 MiB
    float* carry  = (float*)d_ws + (size_t)BB * NCHUNK * 32;        // 4 MiB
    uint4* L      = (uint4*)((float*)d_ws + 2 * (size_t)BB * NCHUNK * 32);  // 16.8 MB

    kA_expm_scan<<<(BB * TT) / 256, 256, 0, stream>>>(hr, hi, L, totals);
    kC_carry    <<<BB, 256, 0, stream>>>(totals, sr, si, carry);
    kD_final    <<<(BB * TT) / 256, 256, 0, stream>>>(L, carry, out);
}

// Round 10
// 123.329 us; speedup vs baseline: 1.3086x; 1.3086x over previous
//
#include <hip/hip_runtime.h>
#include <hip/hip_fp16.h>
#include <cstring>

namespace {

constexpr int    TT     = 2048;
constexpr int    BB     = 128;
constexpr int    CHUNK  = 8;                  // timesteps per chunk (shfl scan width)
constexpr int    NCHUNK = TT / CHUNK;         // 256 chunks per batch
constexpr float  DT     = 0.02f;
constexpr size_t HALF   = (size_t)TT * BB * 16;   // floats per (real|imag) half of d_out

// C = A @ B, complex 4x4, row-major flat [16]
__device__ __forceinline__ void cmm(const float* __restrict__ ar, const float* __restrict__ ai,
                                    const float* __restrict__ br, const float* __restrict__ bi,
                                    float* __restrict__ cr, float* __restrict__ ci) {
#pragma unroll
    for (int i = 0; i < 4; ++i) {
#pragma unroll
        for (int j = 0; j < 4; ++j) {
            float sr = 0.f, si = 0.f;
#pragma unroll
            for (int k = 0; k < 4; ++k) {
                const float xr = ar[i * 4 + k], xi = ai[i * 4 + k];
                const float yr = br[k * 4 + j], yi = bi[k * 4 + j];
                sr = fmaf(xr, yr, sr);
                sr = fmaf(-xi, yi, sr);
                si = fmaf(xr, yi, si);
                si = fmaf(xi, yr, si);
            }
            cr[i * 4 + j] = sr;
            ci[i * 4 + j] = si;
        }
    }
}

// fp16 RNE pack: two f32 -> one uint (lo = a, hi = b)
__device__ __forceinline__ unsigned int pkh(float a, float b) {
    __half2 h = __floats2half2_rn(a, b);
    unsigned int u;
    __builtin_memcpy(&u, &h, 4);
    return u;
}
__device__ __forceinline__ float2 uph(unsigned int u) {
    __half2 h;
    __builtin_memcpy(&h, &u, 4);
    return __half22float2(h);
}

} // namespace

// ---------------------------------------------------------------------------
// kA: expm (deg-4 PS Taylor) + 8-lane Kogge-Stone chunk prefix.
//   Scan shuffle: src = lane-d (clamped), pred = sub>=d  [verified form].
//   gid = b*TT + t -> H read and L write fully coalesced. NO nontemporal
//   hints anywhere: R9 showed nt stores break L2 write-combining of the
//   16B-interleaved layout (2.8x WRITE amplification, kD 10->56 us).
//   L fp16-RNE packed: 4 uint4 per matrix (re 2, im 2) at [b][t].
// ---------------------------------------------------------------------------
__global__ __launch_bounds__(256) void kA_expm_scan(const float* __restrict__ hr,
                                                    const float* __restrict__ hi,
                                                    uint4* __restrict__ L,
                                                    float* __restrict__ totals) {
    const int gid  = blockIdx.x * 256 + threadIdx.x;  // b*TT + t
    const int b    = gid >> 11;
    const int t    = gid & (TT - 1);
    const int sub  = t & (CHUNK - 1);
    const int c    = t >> 3;                          // chunk within batch
    const int lane = threadIdx.x & 63;

    // ---- load A = -i*DT*H: a_r = DT*hi, a_i = -DT*hr (coalesced)
    float a_r[16], a_i[16];
    {
        const float4* p4r = reinterpret_cast<const float4*>(hr) + (size_t)gid * 4;
        const float4* p4i = reinterpret_cast<const float4*>(hi) + (size_t)gid * 4;
#pragma unroll
        for (int v = 0; v < 4; ++v) {
            const float4 rr = p4r[v];
            const float4 im = p4i[v];
            a_r[v * 4 + 0] = DT * im.x;  a_i[v * 4 + 0] = -DT * rr.x;
            a_r[v * 4 + 1] = DT * im.y;  a_i[v * 4 + 1] = -DT * rr.y;
            a_r[v * 4 + 2] = DT * im.z;  a_i[v * 4 + 2] = -DT * rr.z;
            a_r[v * 4 + 3] = DT * im.w;  a_i[v * 4 + 3] = -DT * rr.w;
        }
    }

    // ---- expm deg-4 PS: E = I + A + A2 @ (I/2 + A/6 + A2/24)
    float er[16], ei[16];
    {
        float a2r[16], a2i[16];
        cmm(a_r, a_i, a_r, a_i, a2r, a2i);
        float tr[16], ti[16];
#pragma unroll
        for (int e = 0; e < 16; ++e) {
            const float d = (e % 5 == 0) ? 1.0f : 0.0f;
            tr[e] = fmaf(a_r[e], 1.f / 6.f, d * 0.5f);
            tr[e] = fmaf(a2r[e], 1.f / 24.f, tr[e]);
            ti[e] = a_i[e] * (1.f / 6.f);
            ti[e] = fmaf(a2i[e], 1.f / 24.f, ti[e]);
        }
        cmm(a2r, a2i, tr, ti, er, ei);
#pragma unroll
        for (int e = 0; e < 16; ++e) {
            const float d = (e % 5 == 0) ? 1.0f : 0.0f;
            er[e] = er[e] + d + a_r[e];
            ei[e] = ei[e] + a_i[e];
        }
    }

    // ---- 8-lane Kogge-Stone inclusive prefix (3 rounds), verified form
#pragma unroll
    for (int d = 1; d < CHUNK; d <<= 1) {
        int src = lane - d;
        if (src < 0) src = 0;               // clamped junk, discarded by select
        float qr[16], qi[16];
#pragma unroll
        for (int e = 0; e < 16; ++e) {
            qr[e] = __shfl(er[e], src, 64);
            qi[e] = __shfl(ei[e], src, 64);
        }
        float nr[16], ni[16];
        cmm(er, ei, qr, qi, nr, ni);
        const bool pred = (sub >= d);
#pragma unroll
        for (int e = 0; e < 16; ++e) {
            er[e] = pred ? nr[e] : er[e];
            ei[e] = pred ? ni[e] : ei[e];
        }
    }

    // ---- chunk totals (f32)
    if (sub == CHUNK - 1) {
        float* tp = totals + ((size_t)b * NCHUNK + c) * 32;
#pragma unroll
        for (int e = 0; e < 16; ++e) {
            tp[e]      = er[e];
            tp[16 + e] = ei[e];
        }
    }

    // ---- L fp16-RNE packed, coalesced: 4 uint4 per matrix
    {
        uint4 w0, w1, w2, w3;
        w0.x = pkh(er[0],  er[1]);   w0.y = pkh(er[2],  er[3]);
        w0.z = pkh(er[4],  er[5]);   w0.w = pkh(er[6],  er[7]);
        w1.x = pkh(er[8],  er[9]);   w1.y = pkh(er[10], er[11]);
        w1.z = pkh(er[12], er[13]);  w1.w = pkh(er[14], er[15]);
        w2.x = pkh(ei[0],  ei[1]);   w2.y = pkh(ei[2],  ei[3]);
        w2.z = pkh(ei[4],  ei[5]);   w2.w = pkh(ei[6],  ei[7]);
        w3.x = pkh(ei[8],  ei[9]);   w3.y = pkh(ei[10], ei[11]);
        w3.z = pkh(ei[12], ei[13]);  w3.w = pkh(ei[14], ei[15]);
        uint4* Lp = L + (size_t)gid * 4;
        Lp[0] = w0; Lp[1] = w1; Lp[2] = w2; Lp[3] = w3;
    }
}

// ---------------------------------------------------------------------------
// kC: carries. One block per batch (256 threads = 256 chunks).
//   M[0] = state0[b], M[ct] = total[b][ct-1]; 8-round KS in LDS (SoA).
// ---------------------------------------------------------------------------
__global__ __launch_bounds__(256) void kC_carry(const float* __restrict__ totals,
                                                const float* __restrict__ sr,
                                                const float* __restrict__ si,
                                                float* __restrict__ carry) {
    __shared__ float sRe[16][NCHUNK];
    __shared__ float sIm[16][NCHUNK];

    const int ct = threadIdx.x;             // 0..255
    const int b  = blockIdx.x;

    float pr[16], pi[16];
    if (ct == 0) {
#pragma unroll
        for (int e = 0; e < 16; ++e) {
            pr[e] = sr[b * 16 + e];
            pi[e] = si[b * 16 + e];
        }
    } else {
        const float* tp = totals + ((size_t)b * NCHUNK + ct - 1) * 32;
#pragma unroll
        for (int e = 0; e < 16; ++e) {
            pr[e] = tp[e];
            pi[e] = tp[16 + e];
        }
    }

#pragma unroll
    for (int e = 0; e < 16; ++e) {
        sRe[e][ct] = pr[e];
        sIm[e][ct] = pi[e];
    }
    __syncthreads();

#pragma unroll
    for (int d = 1; d < NCHUNK; d <<= 1) {
        if (ct >= d) {
            float qr[16], qi[16];
#pragma unroll
            for (int e = 0; e < 16; ++e) {
                qr[e] = sRe[e][ct - d];
                qi[e] = sIm[e][ct - d];
            }
            float nr[16], ni[16];
            cmm(pr, pi, qr, qi, nr, ni);
#pragma unroll
            for (int e = 0; e < 16; ++e) {
                pr[e] = nr[e];
                pi[e] = ni[e];
            }
        }
        __syncthreads();
        if (ct >= d) {
#pragma unroll
            for (int e = 0; e < 16; ++e) {
                sRe[e][ct] = pr[e];
                sIm[e][ct] = pi[e];
            }
        }
        __syncthreads();
    }

    float* cp = carry + ((size_t)b * NCHUNK + ct) * 32;
#pragma unroll
    for (int e = 0; e < 16; ++e) {
        cp[e]      = pr[e];
        cp[16 + e] = pi[e];
    }
}

// ---------------------------------------------------------------------------
// kD: out[t,b] = L[b,t] @ carry[b][t/8], [b][t] -> [t][b] via LDS transpose.
// XCD-aligned block swizzle for L2 locality on the L read. Plain cached
// stores so L2 write-combines the interleaved 16B segments into full lines.
// ---------------------------------------------------------------------------
__global__ __launch_bounds__(256) void kD_final(const uint4* __restrict__ L,
                                                const float* __restrict__ carry,
                                                float* __restrict__ out) {
    __shared__ float lds[32 * 16 * 17];     // [e 0..31][bloc][tloc(+pad)]

    const int g     = blockIdx.x;           // 0..1023
    const int tileT = (g & 7) * 16 + ((g >> 3) & 15);   // XCD-aligned: (tileT/16)%8 == g%8
    const int tileB = g >> 7;               // 0..7
    const int t0 = tileT * 16, b0 = tileB * 16;
    const int tid = threadIdx.x;

    // ---- phase 1: read L (fp16) coalesced, multiply by carry, stage to LDS
    {
        const int bloc = tid >> 4, tloc = tid & 15;
        const int tt = t0 + tloc;
        const size_t gi = ((size_t)(b0 + bloc) * TT + tt);

        const uint4* Lp = L + gi * 4;
        const uint4 w0 = Lp[0], w1 = Lp[1], w2 = Lp[2], w3 = Lp[3];
        float l_r[16], l_i[16];
        {
            float2 p;
            p = uph(w0.x); l_r[0]  = p.x; l_r[1]  = p.y;
            p = uph(w0.y); l_r[2]  = p.x; l_r[3]  = p.y;
            p = uph(w0.z); l_r[4]  = p.x; l_r[5]  = p.y;
            p = uph(w0.w); l_r[6]  = p.x; l_r[7]  = p.y;
            p = uph(w1.x); l_r[8]  = p.x; l_r[9]  = p.y;
            p = uph(w1.y); l_r[10] = p.x; l_r[11] = p.y;
            p = uph(w1.z); l_r[12] = p.x; l_r[13] = p.y;
            p = uph(w1.w); l_r[14] = p.x; l_r[15] = p.y;
            p = uph(w2.x); l_i[0]  = p.x; l_i[1]  = p.y;
            p = uph(w2.y); l_i[2]  = p.x; l_i[3]  = p.y;
            p = uph(w2.z); l_i[4]  = p.x; l_i[5]  = p.y;
            p = uph(w2.w); l_i[6]  = p.x; l_i[7]  = p.y;
            p = uph(w3.x); l_i[8]  = p.x; l_i[9]  = p.y;
            p = uph(w3.y); l_i[10] = p.x; l_i[11] = p.y;
            p = uph(w3.z); l_i[12] = p.x; l_i[13] = p.y;
            p = uph(w3.w); l_i[14] = p.x; l_i[15] = p.y;
        }

        float c_r[16], c_i[16];
        const float* cp = carry + ((size_t)(b0 + bloc) * NCHUNK + (tt >> 3)) * 32;
#pragma unroll
        for (int e = 0; e < 16; ++e) {
            c_r[e] = cp[e];
            c_i[e] = cp[16 + e];
        }

        float o_r[16], o_i[16];
        cmm(l_r, l_i, c_r, c_i, o_r, o_i);

        const int slot = bloc * 17 + tloc;
#pragma unroll
        for (int e = 0; e < 16; ++e) {
            lds[e * 272 + slot]        = o_r[e];
            lds[(e + 16) * 272 + slot] = o_i[e];
        }
    }
    __syncthreads();

    // ---- phase 2: read transposed from LDS, write out coalesced in [t][b]
    {
        const int u = tid >> 4;             // t offset in tile
        const int v = tid & 15;             // b offset in tile
        const int slot = v * 17 + u;

        float r2[16], i2[16];
#pragma unroll
        for (int e = 0; e < 16; ++e) {
            r2[e] = lds[e * 272 + slot];
            i2[e] = lds[(e + 16) * 272 + slot];
        }

        const size_t oi = ((size_t)(t0 + u) * BB + (b0 + v)) * 16;
        float4* orp = reinterpret_cast<float4*>(out + oi);
        float4* oip = reinterpret_cast<float4*>(out + HALF + oi);
#pragma unroll
        for (int w = 0; w < 4; ++w) {
            orp[w] = make_float4(r2[w * 4 + 0], r2[w * 4 + 1], r2[w * 4 + 2], r2[w * 4 + 3]);
            oip[w] = make_float4(i2[w * 4 + 0], i2[w * 4 + 1], i2[w * 4 + 2], i2[w * 4 + 3]);
        }
    }
}

extern "C" void kernel_launch(void* const* d_in, const int* in_sizes, int n_in,
                              void* d_out, int out_size, void* d_ws, size_t ws_size,
                              hipStream_t stream) {
    const float* hr = (const float*)d_in[0];
    const float* hi = (const float*)d_in[1];
    const float* sr = (const float*)d_in[2];
    const float* si = (const float*)d_in[3];
    float* out    = (float*)d_out;
    float* totals = (float*)d_ws;                                   // 4 MiB
    float* carry  = (float*)d_ws + (size_t)BB * NCHUNK * 32;        // 4 MiB
    uint4* L      = (uint4*)((float*)d_ws + 2 * (size_t)BB * NCHUNK * 32);  // 16.8 MB

    kA_expm_scan<<<(BB * TT) / 256, 256, 0, stream>>>(hr, hi, L, totals);
    kC_carry    <<<BB, 256, 0, stream>>>(totals, sr, si, carry);
    kD_final    <<<(BB * TT) / 256, 256, 0, stream>>>(L, carry, out);
}